// Round 1
// 299.888 us; speedup vs baseline: 1.1984x; 1.1984x over previous
//
#include <hip/hip_runtime.h>
#include <stdint.h>

#define N_BATCH 32
#define CHN     256
#define HW      56
#define HP      58

// xpad layout (uint4 "cells" of 4 u32 = 128 channel-bits):
//   cell(n, hp, h, wp) = ((n*58 + hp)*2 + h)*58 + wp,  h = channel-half
#define XPAD_CELLS (N_BATCH * HP * 2 * HP)   // 215,296 cells
#define XPAD_U32   (XPAD_CELLS * 4)

// ---------------- fused prep (UNCHANGED from verified baseline) -------------
// blocks [0,784):   binx — thread = (pixel, channel-half), coalesced uint4 write
// blocks [784,841): border zero-fill (replaces memset)
// blocks [841,1097): binw via ballot
__global__ __launch_bounds__(256) void prep_kernel(const float* __restrict__ x,
                                                   const float* __restrict__ wsrc,
                                                   uint32_t* __restrict__ xpad,
                                                   uint32_t* __restrict__ wbits,
                                                   int* __restrict__ wpop) {
    __shared__ int part[9][4];
    int bid  = blockIdx.x;
    int t    = threadIdx.x;
    int lane = t & 63;

    if (bid < 784) {
        // ---- binx: one full cell (4 words = 128 channels) per thread ----
        int tid = bid * 256 + t;          // 0..200703
        int n   = tid / 6272;             // 6272 = 3136 px * 2 halves
        int rem = tid - n * 6272;
        int hf  = rem / 3136;             // channel half (wave-uniform: 3136=49 waves)
        int pq  = rem - hf * 3136;        // pixel in plane; lane-consecutive

        const float* src = x + ((size_t)(n * 256 + hf * 128)) * 3136 + pq;
        uint32_t b0 = 0, b1 = 0, b2 = 0, b3 = 0;
#pragma unroll
        for (int g = 0; g < 8; g++) {
            float v[16];
#pragma unroll
            for (int i = 0; i < 16; i++) v[i] = src[(size_t)(g * 16 + i) * 3136];
#pragma unroll
            for (int i = 0; i < 16; i++) {
                int c = g * 16 + i;       // 0..127 within half
                uint32_t b = v[i] > 0.0f ? 1u : 0u;
                if ((c >> 5) == 0) b0 |= b << (c & 31);
                else if ((c >> 5) == 1) b1 |= b << (c & 31);
                else if ((c >> 5) == 2) b2 |= b << (c & 31);
                else b3 |= b << (c & 31);
            }
        }
        int h = pq / 56;
        int w = pq - h * 56;
        uint32_t cell = ((uint32_t)(n * HP + h + 1) * 2 + hf) * HP + (w + 1);
        ((uint4*)xpad)[cell] = make_uint4(b0, b1, b2, b3);   // 16B/lane, coalesced
    } else if (bid < 841) {
        // ---- border zero-fill: 14,592 border cells ----
        int u = (bid - 784) * 256 + t;
        if (u < 14592) {
            int p = u / 228;
            int e = u - p * 228;
            int n = p >> 1, h = p & 1;
            int hp, wp;
            if (e < 58)       { hp = 0;       wp = e;       }
            else if (e < 116) { hp = 57;      wp = e - 58;  }
            else if (e < 172) { hp = e - 115; wp = 0;       }
            else              { hp = e - 171; wp = 57;      }
            uint32_t cell = ((uint32_t)(n * HP + hp) * 2 + h) * HP + wp;
            ((uint4*)xpad)[cell] = make_uint4(0u, 0u, 0u, 0u);
        }
    } else {
        // ---- binw via ballot ----
        int o  = bid - 841;
        int wv = t >> 6;
        const float* p = wsrc + ((size_t)o * 256 + t) * 9;
        float v[9];
#pragma unroll
        for (int tap = 0; tap < 9; tap++) v[tap] = p[tap];
#pragma unroll
        for (int tap = 0; tap < 9; tap++) {
            unsigned long long m = __ballot(v[tap] > 0.0f);
            if (lane == 0) {
                wbits[(size_t)(o * 9 + tap) * 8 + 2 * wv]     = (uint32_t)m;
                wbits[(size_t)(o * 9 + tap) * 8 + 2 * wv + 1] = (uint32_t)(m >> 32);
                part[tap][wv] = __builtin_popcountll(m);
            }
        }
        __syncthreads();
        if (t < 9) wpop[o * 9 + t] = part[t][0] + part[t][1] + part[t][2] + part[t][3];
    }
}

// ---------------- binary conv: lane = output channel ------------------------
// Block = (output row h, batch n). 4 waves; wave wv covers o = wv*64 + lane.
// W (72 u32) resident in VGPRs per lane; X broadcast from a 3-row LDS strip.
// Output transposed o<->w through a padded per-wave LDS buffer for coalesced
// NCHW row stores.
__global__ __launch_bounds__(256, 2)
void conv_kernel(const uint32_t* __restrict__ xpad,
                 const uint32_t* __restrict__ wbits,
                 const int* __restrict__ wpop,
                 float* __restrict__ out) {
    __shared__ uint4 sx[3 * 2 * HP];          // 348 cells = 5,568 B
    __shared__ float obuf[4 * 64 * 57];       // 58,368 B  (57: stride coprime w/ 32 banks)

    int t    = threadIdx.x;
    int lane = t & 63;
    int wv   = t >> 6;
    int h    = blockIdx.x;                    // output row 0..55
    int n    = blockIdx.y;

    // stage padded input rows h..h+2 (contiguous 348 cells in xpad)
    const uint4* xg = (const uint4*)xpad + ((size_t)n * HP + h) * (2 * HP);
    for (int i = t; i < 3 * 2 * HP; i += 256) sx[i] = xg[i];

    // per-lane weights: o = wv*64 + lane, 72 words = 18 uint4, loaded ONCE
    int o = wv * 64 + lane;
    const uint4* wsrc4 = (const uint4*)(wbits + (size_t)o * 72);
    uint4 W4[18];
#pragma unroll
    for (int i = 0; i < 18; i++) W4[i] = wsrc4[i];

    const int* wpa = wpop + (size_t)o * 9;
    int pa[9];
#pragma unroll
    for (int i = 0; i < 9; i++) pa[i] = wpa[i];

    __syncthreads();

    float* ob = obuf + wv * (64 * 57);
    bool hedge = (h == 0) | (h == 55);

#pragma unroll 2
    for (int w = 0; w < 56; w++) {
        const uint4* cb = sx + w;             // wave-uniform base; 18 imm offsets
        int a0 = 0, a1 = 0, a2 = 0, a3 = 0;   // 4 independent popcount chains
#pragma unroll
        for (int r = 0; r < 3; r++)
#pragma unroll
            for (int dw = 0; dw < 3; dw++)
#pragma unroll
                for (int hf = 0; hf < 2; hf++) {
                    uint4 Xc = cb[(r * 2 + hf) * HP + dw];      // broadcast ds_read_b128
                    uint4 Wc = W4[(r * 3 + dw) * 2 + hf];
                    a0 += __builtin_popcount(Xc.x ^ Wc.x);
                    a1 += __builtin_popcount(Xc.y ^ Wc.y);
                    a2 += __builtin_popcount(Xc.z ^ Wc.z);
                    a3 += __builtin_popcount(Xc.w ^ Wc.w);
                }
        int va = 2304 - 2 * ((a0 + a1) + (a2 + a3));
        if (hedge | (w == 0) | (w == 55)) {   // wave-uniform branch
            int ca = 0;
#pragma unroll
            for (int dh = 0; dh < 3; dh++)
#pragma unroll
                for (int dw = 0; dw < 3; dw++)
                    if ((unsigned)(h + dh - 1) >= 56u || (unsigned)(w + dw - 1) >= 56u)
                        ca += 256 - 2 * pa[dh * 3 + dw];
            va -= ca;
        }
        ob[lane * 57 + w] = (float)va;        // stride 57: conflict-free
    }

    __syncthreads();                          // drain obuf (within-wave RAW; cheap safety)

    // drain: lane = w (coalesced 224B stores), loop over this wave's 64 o's
    if (lane < 56) {
        float* orow = out + (((size_t)n * 256 + wv * 64) * 56 + h) * 56 + lane;
#pragma unroll 8
        for (int o2 = 0; o2 < 64; o2++)
            orow[(size_t)o2 * 3136] = ob[o2 * 57 + lane];
    }
}

extern "C" void kernel_launch(void* const* d_in, const int* in_sizes, int n_in,
                              void* d_out, int out_size, void* d_ws, size_t ws_size,
                              hipStream_t stream) {
    const float* x    = (const float*)d_in[0];
    const float* wsrc = (const float*)d_in[1];
    float* out = (float*)d_out;

    uint32_t* xpad  = (uint32_t*)d_ws;                    // 3.44 MB
    uint32_t* wbits = xpad + XPAD_U32;                    // 18432 u32
    int*      wpop  = (int*)(wbits + 256 * 9 * 8);        // 2304 int

    prep_kernel<<<1097, 256, 0, stream>>>(x, wsrc, xpad, wbits, wpop);
    conv_kernel<<<dim3(HW, N_BATCH), 256, 0, stream>>>(xpad, wbits, wpop, out);
}